// Round 9
// baseline (33.868 us; speedup 1.0000x reference)
//
#include <hip/hip_runtime.h>

#define BIGV 1e9f
#define NPT 256            // N == M == 256

// band: |i-j| <= 51.  i-window on diagonal s:
__device__ __forceinline__ int imin_of(int s){
    int a = s - 255; if (a < 0) a = 0;            // j = s-i <= 255
    int c = s - 50;  c = (c > 0) ? (c >> 1) : 0;  // ceil((s-51)/2)
    return (a > c) ? a : c;
}
__device__ __forceinline__ int imax_of(int s){
    int a = (s < 255) ? s : 255;
    int c = (s + 51) >> 1;                        // floor((s+51)/2)
    return (a < c) ? a : c;
}

// wave-wide shift by 1 with BIG fill (no LDS): lane l <- x[l-1]
__device__ __forceinline__ float dpp_shr1(float x){
    return __int_as_float(__builtin_amdgcn_update_dpp(
        __float_as_int(BIGV), __float_as_int(x), 0x138 /*WAVE_SHR1*/, 0xF, 0xF, false));
}
__device__ __forceinline__ float dpp_shl1(float x){
    return __int_as_float(__builtin_amdgcn_update_dpp(
        __float_as_int(BIGV), __float_as_int(x), 0x130 /*WAVE_SHL1*/, 0xF, 0xF, false));
}

__device__ __forceinline__ float min3f(float a, float b, float c){
    float r;
    asm("v_min3_f32 %0, %1, %2, %3" : "=v"(r) : "v"(a), "v"(b), "v"(c));
    return r;
}

// ---------------- Kernel A: banded distances -> full f32 rows in d_ws ------------
// Df layout: f32, row (b*512 + s) has 256 floats (i = 0..255), BIG outside band.
// grid = 256 blocks: batch = idx & 15, chunk = idx >> 4 (32 diagonals each).
__global__ __launch_bounds__(256, 1) void ldtw_dist(const float* __restrict__ X,
                                                    const float* __restrict__ Y,
                                                    float* __restrict__ Df)
{
    __shared__ float4 Xs[80*17];
    __shared__ float4 Ys[80*17];
    __shared__ float nX[80], nY[80];
    __shared__ float Band[32*65];   // pitch 65
    const int b  = blockIdx.x & 15;
    const int c  = blockIdx.x >> 4;       // 0..15, 32 diagonals each
    const int s0 = c << 5;
    const int s1 = (s0 + 31 > 510) ? 510 : (s0 + 31);
    const int ilo = imin_of(s0), ihi = imax_of(s1);
    const int jlo = s0 - imax_of(s0), jhi = s1 - imin_of(s1);
    const int nx = ihi - ilo + 1, ny = jhi - jlo + 1;   // each <= 68
    const int t = threadIdx.x;
    const float4* Xb = (const float4*)(X + (size_t)b * NPT * 64);
    const float4* Yb = (const float4*)(Y + (size_t)b * NPT * 64);

    for (int idx = t; idx < nx * 16; idx += 256){
        int r = idx >> 4, k = idx & 15;
        Xs[r*17 + k] = Xb[(ilo + r)*16 + k];
    }
    for (int idx = t; idx < ny * 16; idx += 256){
        int r = idx >> 4, k = idx & 15;
        Ys[r*17 + k] = Yb[(jlo + r)*16 + k];
    }
    __syncthreads();

    for (int r = t; r < nx + ny; r += 256){
        const float4* row = (r < nx) ? (Xs + r*17) : (Ys + (r - nx)*17);
        float acc = 0.f;
        #pragma unroll
        for (int k = 0; k < 16; ++k){
            float4 v = row[k];
            acc += v.x*v.x + v.y*v.y + v.z*v.z + v.w*v.w;
        }
        if (r < nx) nX[r] = acc; else nY[r - nx] = acc;
    }
    __syncthreads();

    // phase 1: 5x5 register-tiled dot products over the covering rectangle
    {
        const int ti = t >> 4;       // 0..15
        const int tj = t & 15;       // 0..15
        float acc[5][5];
        #pragma unroll
        for (int u = 0; u < 5; ++u)
            #pragma unroll
            for (int v = 0; v < 5; ++v) acc[u][v] = 0.f;

        #pragma unroll 4
        for (int k = 0; k < 16; ++k){
            float4 xa[5], ya[5];
            #pragma unroll
            for (int u = 0; u < 5; ++u){
                xa[u] = Xs[(ti + u*16)*17 + k];
                ya[u] = Ys[(tj + u*16)*17 + k];
            }
            #pragma unroll
            for (int u = 0; u < 5; ++u)
                #pragma unroll
                for (int v = 0; v < 5; ++v)
                    acc[u][v] += xa[u].x*ya[v].x + xa[u].y*ya[v].y
                               + xa[u].z*ya[v].z + xa[u].w*ya[v].w;
        }

        #pragma unroll
        for (int u = 0; u < 5; ++u){
            #pragma unroll
            for (int v = 0; v < 5; ++v){
                const int iloc = ti + u*16, jloc = tj + v*16;
                const int i = ilo + iloc, j = jlo + jloc;
                const int s = i + j;
                if (s >= s0 && s <= s1){
                    const int im = imin_of(s), ix = imax_of(s);
                    if (i >= im && i <= ix)
                        Band[(s - s0)*65 + (i - im)] =
                            nX[iloc] + nY[jloc] - 2.f*acc[u][v];
                }
            }
        }
    }
    __syncthreads();

    // phase 2: emit full 256-wide f32 rows (BIG outside band), coalesced float4
    float4* Df4 = (float4*)Df;
    const size_t rowbase4 = ((size_t)(b * 512 + s0)) << 6;   // float4 units, 64/row
    for (int slot = t; slot < 32*64; slot += 256){
        const int sd = slot >> 6, q = slot & 63;
        const int s  = s0 + sd;
        float4 v = make_float4(BIGV, BIGV, BIGV, BIGV);
        if (s <= 510){
            const int im = imin_of(s), ix = imax_of(s);
            const int i0 = q << 2;
            if (i0 + 0 >= im && i0 + 0 <= ix) v.x = Band[sd*65 + (i0 + 0 - im)];
            if (i0 + 1 >= im && i0 + 1 <= ix) v.y = Band[sd*65 + (i0 + 1 - im)];
            if (i0 + 2 >= im && i0 + 2 <= ix) v.z = Band[sd*65 + (i0 + 2 - im)];
            if (i0 + 3 >= im && i0 + 3 <= ix) v.w = Band[sd*65 + (i0 + 3 - im)];
        }
        Df4[rowbase4 + ((size_t)sd << 6) + q] = v;
    }
}

// ---------------- Kernel B: absolute-i DP + 3 L2-warmer waves --------------------
// wave 0: 4 cells/lane DP with 4-deep register prefetch (unchanged).
// waves 1-3: touch one dword per 128B line of the whole 512KB batch slab to pull
// it into the local L2 (~22 concurrent scalar loads/lane), then exit.
__global__ __launch_bounds__(256, 1) void ldtw_dp(const float* __restrict__ Df,
                                                  float* __restrict__ out)
{
    const int b = blockIdx.x;
    const int wv = threadIdx.x >> 6;
    if (wv != 0){
        const int lane = threadIdx.x - 64;            // 0..191 across waves 1-3
        const float* p = Df + ((size_t)b << 17);      // 131072 floats = 512KB
        float acc = 0.f;
        #pragma unroll
        for (int k = 0; k < 22; ++k){
            int idx = (lane + k*192) << 5;            // stride 32 floats = 128B line
            if (idx < 131072) acc += p[idx];
        }
        asm volatile("" :: "v"(acc));                 // keep the warming loads live
        return;
    }

    const int L = threadIdx.x;                        // 0..63, cells i = 4L..4L+3
    const float4* base = (const float4*)Df + ((size_t)b << 15) + L;  // row stride 64

    float p0, p1, p2, p3, q0, q1, q2, q3;
    float d00 = Df[(size_t)b << 17];                  // D(0,0)
    p0 = (L == 0) ? d00 : BIGV; p1 = BIGV; p2 = BIGV; p3 = BIGV;
    q0 = BIGV; q1 = BIGV; q2 = BIGV; q3 = BIGV;

    // group g covers s = 8g+1 .. 8g+8; two bases keep imm offsets within 4KB
#define LOADG(Bk, g) { \
    const float4* r0_ = base + (size_t)(((g) << 3) + 1) * 64; \
    const float4* r1_ = r0_ + 256; \
    Bk##0 = r0_[0];   Bk##1 = r0_[64];  Bk##2 = r0_[128]; Bk##3 = r0_[192]; \
    Bk##4 = r1_[0];   Bk##5 = r1_[64];  Bk##6 = r1_[128]; Bk##7 = r1_[192]; }

    // prev1 = p, prev2 = q -> new into q (q becomes prev1)
#define STEP_PQ(V) { \
    float s1_ = dpp_shr1(p3), s2_ = dpp_shr1(q3); \
    float n0 = min3f(s1_, p0, s2_) + (V).x; \
    float n1 = min3f(p0, p1, q0) + (V).y; \
    float n2 = min3f(p1, p2, q1) + (V).z; \
    float n3 = min3f(p2, p3, q2) + (V).w; \
    q0 = n0; q1 = n1; q2 = n2; q3 = n3; }
#define STEP_QP(V) { \
    float s1_ = dpp_shr1(q3), s2_ = dpp_shr1(p3); \
    float n0 = min3f(s1_, q0, s2_) + (V).x; \
    float n1 = min3f(q0, q1, p0) + (V).y; \
    float n2 = min3f(q1, q2, p1) + (V).z; \
    float n3 = min3f(q2, q3, p2) + (V).w; \
    p0 = n0; p1 = n1; p2 = n2; p3 = n3; }

#define GROUP8(Bk) \
    STEP_PQ(Bk##0) STEP_QP(Bk##1) STEP_PQ(Bk##2) STEP_QP(Bk##3) \
    STEP_PQ(Bk##4) STEP_QP(Bk##5) STEP_PQ(Bk##6) STEP_QP(Bk##7)

    float4 A0,A1,A2,A3,A4,A5,A6,A7;
    float4 B0,B1,B2,B3,B4,B5,B6,B7;
    float4 C0,C1,C2,C3,C4,C5,C6,C7;
    float4 E0,E1,E2,E3,E4,E5,E6,E7;
    LOADG(A, 0) LOADG(B, 1) LOADG(C, 2) LOADG(E, 3)
    for (int m = 0; m < 60; m += 4){       // consumes groups 0..59 (s = 1..480)
        GROUP8(A) LOADG(A, m + 4)
        GROUP8(B) LOADG(B, m + 5)
        GROUP8(C) LOADG(C, m + 6)
        GROUP8(E) LOADG(E, m + 7)
    }
    GROUP8(A)                               // group 60: s = 481..488
    GROUP8(B)                               // group 61: s = 489..496
    GROUP8(C)                               // group 62: s = 497..504
    STEP_PQ(E0) STEP_QP(E1) STEP_PQ(E2) STEP_QP(E3) STEP_PQ(E4) STEP_QP(E5) // 505..510

    if (L == 63) out[b] = p3;               // dp[510][255]
#undef LOADG
#undef STEP_PQ
#undef STEP_QP
#undef GROUP8
}

// ---------------- Fallback (tiny ws): fused, D on the fly ----------------
__device__ __forceinline__ float cell_d(const float4* __restrict__ Xb,
                                        const float4* __restrict__ Yb,
                                        int i, int j)
{
    const float4* xr = Xb + i*16;
    const float4* yr = Yb + j*16;
    float acc = 0.f;
    #pragma unroll
    for (int k = 0; k < 16; ++k){
        float4 a = xr[k], bb = yr[k];
        float dx = a.x-bb.x, dy = a.y-bb.y, dz = a.z-bb.z, dw = a.w-bb.w;
        acc += dx*dx + dy*dy + dz*dz + dw*dw;
    }
    return acc;
}

__global__ __launch_bounds__(64) void ldtw_fused_fb(const float* __restrict__ X,
                                                    const float* __restrict__ Y,
                                                    float* __restrict__ out)
{
    const int b = blockIdx.x;
    const int l = threadIdx.x;
    const float4* Xb = (const float4*)(X + (size_t)b * NPT * 64);
    const float4* Yb = (const float4*)(Y + (size_t)b * NPT * 64);
    float prev1 = (l == 0) ? cell_d(Xb, Yb, 0, 0) : BIGV;
    float prev2 = BIGV;
    int base1 = 0, base2 = 0;
    for (int s = 1; s <= 510; ++s){
        const int im = imin_of(s);
        const int ix = imax_of(s);
        const int i  = im + l;
        const bool act = (i <= ix);
        const int ic = act ? i : ix;
        const int j  = s - ic;
        float Dv = cell_d(Xb, Yb, ic, j);
        const int d1 = im - base1, d2 = im - base2;
        float sr1 = dpp_shr1(prev1), sl1 = dpp_shl1(prev1);
        float sr2 = dpp_shr1(prev2), sl2 = dpp_shl1(prev2);
        float m1 = d1 ? fminf(prev1, sl1) : fminf(sr1, prev1);
        float vd = (d2 == 0) ? sr2 : ((d2 == 2) ? sl2 : prev2);
        float m3 = fminf(m1, vd);
        float cur = act ? (m3 + Dv) : BIGV;
        prev2 = prev1; base2 = base1;
        prev1 = cur;   base1 = im;
    }
    if (l == 0) out[b] = prev1;
}

extern "C" void kernel_launch(void* const* d_in, const int* in_sizes, int n_in,
                              void* d_out, int out_size, void* d_ws, size_t ws_size,
                              hipStream_t stream)
{
    const float* X = (const float*)d_in[0];
    const float* Y = (const float*)d_in[1];
    float* out = (float*)d_out;
    const int Bn = in_sizes[0] / (NPT * 64);     // = 16
    // Df: Bn * 512 rows * 256 f32 = Bn * 512 KiB; + slack for tail over-read
    const size_t need = (size_t)Bn * 512 * 256 * 4 + 65536;
    if (ws_size >= need && Bn == 16){
        float* Df = (float*)d_ws;
        hipLaunchKernelGGL(ldtw_dist, dim3(256),  dim3(256), 0, stream, X, Y, Df);
        hipLaunchKernelGGL(ldtw_dp,   dim3(Bn),   dim3(256), 0, stream, Df, out);
    } else {
        hipLaunchKernelGGL(ldtw_fused_fb, dim3(Bn), dim3(64), 0, stream, X, Y, out);
    }
}

// Round 10
// 31.816 us; speedup vs baseline: 1.0645x; 1.0645x over previous
//
#include <hip/hip_runtime.h>

#define BIGV 1e9f
#define NPT 256            // N == M == 256

// band: |i-j| <= 51.  i-window on diagonal s:
__device__ __forceinline__ int imin_of(int s){
    int a = s - 255; if (a < 0) a = 0;            // j = s-i <= 255
    int c = s - 50;  c = (c > 0) ? (c >> 1) : 0;  // ceil((s-51)/2)
    return (a > c) ? a : c;
}
__device__ __forceinline__ int imax_of(int s){
    int a = (s < 255) ? s : 255;
    int c = (s + 51) >> 1;                        // floor((s+51)/2)
    return (a < c) ? a : c;
}

// window base for group g (rows s = 8g+1 .. 8g+8): W <= imin(s)-1 for all s in
// group (keeps band-edge predecessors in-window), clamped to [0,192] so the
// final output cell i=255 sits at lane 63.
__device__ __forceinline__ int Wof(int g){
    int w = imin_of(8*g + 1) - 1;
    return (w < 0) ? 0 : ((w > 192) ? 192 : w);
}
// per-row window base (row 0 uses W=0)
__device__ __forceinline__ int wrow_of(int s){
    return (s == 0) ? 0 : Wof((s - 1) >> 3);
}

// wave-wide shift by 1 with BIG fill (no LDS): lane l <- x[l-1]
__device__ __forceinline__ float dpp_shr1(float x){
    return __int_as_float(__builtin_amdgcn_update_dpp(
        __float_as_int(BIGV), __float_as_int(x), 0x138 /*WAVE_SHR1*/, 0xF, 0xF, false));
}
// lane l <- x[l+1]
__device__ __forceinline__ float dpp_shl1(float x){
    return __int_as_float(__builtin_amdgcn_update_dpp(
        __float_as_int(BIGV), __float_as_int(x), 0x130 /*WAVE_SHL1*/, 0xF, 0xF, false));
}

__device__ __forceinline__ float min3f(float a, float b, float c){
    float r;
    asm("v_min3_f32 %0, %1, %2, %3" : "=v"(r) : "v"(a), "v"(b), "v"(c));
    return r;
}

// ---------------- Kernel A: banded distances -> windowed 64-float rows -----------
// Dwin layout: row (b*512 + s) has 64 floats: col l <-> i = wrow_of(s)+l,
// BIG outside band / i>255. Row 511 all-BIG.
// grid = 256 blocks: batch = idx & 15, chunk = idx >> 4 (32 diagonals each).
__global__ __launch_bounds__(256, 1) void ldtw_dist(const float* __restrict__ X,
                                                    const float* __restrict__ Y,
                                                    float* __restrict__ Dwin)
{
    __shared__ float4 Xs[80*17];
    __shared__ float4 Ys[80*17];
    __shared__ float nX[80], nY[80];
    __shared__ float Band[32*65];   // pitch 65
    const int b  = blockIdx.x & 15;
    const int c  = blockIdx.x >> 4;       // 0..15, 32 diagonals each
    const int s0 = c << 5;
    const int s1 = (s0 + 31 > 510) ? 510 : (s0 + 31);
    const int ilo = imin_of(s0), ihi = imax_of(s1);
    const int jlo = s0 - imax_of(s0), jhi = s1 - imin_of(s1);
    const int nx = ihi - ilo + 1, ny = jhi - jlo + 1;   // each <= 68
    const int t = threadIdx.x;
    const float4* Xb = (const float4*)(X + (size_t)b * NPT * 64);
    const float4* Yb = (const float4*)(Y + (size_t)b * NPT * 64);

    for (int idx = t; idx < nx * 16; idx += 256){
        int r = idx >> 4, k = idx & 15;
        Xs[r*17 + k] = Xb[(ilo + r)*16 + k];
    }
    for (int idx = t; idx < ny * 16; idx += 256){
        int r = idx >> 4, k = idx & 15;
        Ys[r*17 + k] = Yb[(jlo + r)*16 + k];
    }
    __syncthreads();

    for (int r = t; r < nx + ny; r += 256){
        const float4* row = (r < nx) ? (Xs + r*17) : (Ys + (r - nx)*17);
        float acc = 0.f;
        #pragma unroll
        for (int k = 0; k < 16; ++k){
            float4 v = row[k];
            acc += v.x*v.x + v.y*v.y + v.z*v.z + v.w*v.w;
        }
        if (r < nx) nX[r] = acc; else nY[r - nx] = acc;
    }
    __syncthreads();

    // phase 1: 5x5 register-tiled dot products over the covering rectangle.
    // unroll 2: max-live ~130 VGPR -> provably no scratch spill (round-6/7 fix).
    {
        const int ti = t >> 4;       // 0..15
        const int tj = t & 15;       // 0..15
        float acc[5][5];
        #pragma unroll
        for (int u = 0; u < 5; ++u)
            #pragma unroll
            for (int v = 0; v < 5; ++v) acc[u][v] = 0.f;

        #pragma unroll 2
        for (int k = 0; k < 16; ++k){
            float4 xa[5], ya[5];
            #pragma unroll
            for (int u = 0; u < 5; ++u){
                xa[u] = Xs[(ti + u*16)*17 + k];
                ya[u] = Ys[(tj + u*16)*17 + k];
            }
            #pragma unroll
            for (int u = 0; u < 5; ++u)
                #pragma unroll
                for (int v = 0; v < 5; ++v)
                    acc[u][v] += xa[u].x*ya[v].x + xa[u].y*ya[v].y
                               + xa[u].z*ya[v].z + xa[u].w*ya[v].w;
        }

        #pragma unroll
        for (int u = 0; u < 5; ++u){
            #pragma unroll
            for (int v = 0; v < 5; ++v){
                const int iloc = ti + u*16, jloc = tj + v*16;
                const int i = ilo + iloc, j = jlo + jloc;
                const int s = i + j;
                if (s >= s0 && s <= s1){
                    const int im = imin_of(s), ix = imax_of(s);
                    if (i >= im && i <= ix)
                        Band[(s - s0)*65 + (i - im)] =
                            nX[iloc] + nY[jloc] - 2.f*acc[u][v];
                }
            }
        }
    }
    __syncthreads();

    // phase 2: emit windowed 64-float rows (BIG outside band)
    const size_t rowbase = (size_t)(b * 512 + s0) * 64;
    for (int slot = t; slot < 32*64; slot += 256){
        const int sd = slot >> 6, l = slot & 63;
        const int s  = s0 + sd;
        float val = BIGV;
        if (s <= 510){
            const int W = wrow_of(s);
            const int i = W + l;
            const int im = imin_of(s), ix = imax_of(s);
            if (i >= im && i <= ix) val = Band[sd*65 + (i - im)];
        }
        Dwin[rowbase + (size_t)sd*64 + l] = val;
    }
}

// ---------------- Kernel B: windowed DP, 1 cell/lane, 1 wave/batch ---------------
// lane l holds dp at i = W_g + l; between groups shift by d = W_g - W_{g-1} DPPs.
// 8-deep group prefetch: 56 outstanding dwords, ~770cy cover.
__global__ __launch_bounds__(64) void ldtw_dp(const float* __restrict__ Dw,
                                              float* __restrict__ out)
{
    const int b = blockIdx.x;
    const int l = threadIdx.x;
    const float* base = Dw + (size_t)b * 512 * 64 + l;

    float p = base[0];        // row 0 = dp[0] in W=0 window (D00 at lane 0, BIG else)
    float q = BIGV;           // dp[-1]

#define LOADG(Bk, g) { \
    const float* bp_ = base + (size_t)(8*(g) + 1) * 64; \
    Bk##0 = bp_[0];   Bk##1 = bp_[64];  Bk##2 = bp_[128]; Bk##3 = bp_[192]; \
    Bk##4 = bp_[256]; Bk##5 = bp_[320]; Bk##6 = bp_[384]; Bk##7 = bp_[448]; }

#define SHIFTG(g) { \
    int d_ = Wof(g) - Wof((g) - 1); \
    for (int k_ = 0; k_ < d_; ++k_){ p = dpp_shl1(p); q = dpp_shl1(q); } }

#define STEP_PQ(w) q = min3f(dpp_shr1(p), p, dpp_shr1(q)) + (w);
#define STEP_QP(w) p = min3f(dpp_shr1(q), q, dpp_shr1(p)) + (w);

#define GROUPF(Bk, g) { SHIFTG(g) \
    STEP_PQ(Bk##0) STEP_QP(Bk##1) STEP_PQ(Bk##2) STEP_QP(Bk##3) \
    STEP_PQ(Bk##4) STEP_QP(Bk##5) STEP_PQ(Bk##6) STEP_QP(Bk##7) }

    float A0,A1,A2,A3,A4,A5,A6,A7;
    float B0,B1,B2,B3,B4,B5,B6,B7;
    float C0,C1,C2,C3,C4,C5,C6,C7;
    float E0,E1,E2,E3,E4,E5,E6,E7;
    float F0,F1,F2,F3,F4,F5,F6,F7;
    float G0,G1,G2,G3,G4,G5,G6,G7;
    float H0,H1,H2,H3,H4,H5,H6,H7;
    float K0,K1,K2,K3,K4,K5,K6,K7;

    LOADG(A, 0) LOADG(B, 1) LOADG(C, 2) LOADG(E, 3)
    LOADG(F, 4) LOADG(G, 5) LOADG(H, 6) LOADG(K, 7)

    for (int m = 0; m < 56; m += 8){       // consumes groups 0..55 (s = 1..448)
        GROUPF(A, m + 0) LOADG(A, m + 8)
        GROUPF(B, m + 1) LOADG(B, m + 9)
        GROUPF(C, m + 2) LOADG(C, m + 10)
        GROUPF(E, m + 3) LOADG(E, m + 11)
        GROUPF(F, m + 4) LOADG(F, m + 12)
        GROUPF(G, m + 5) LOADG(G, m + 13)
        GROUPF(H, m + 6) LOADG(H, m + 14)
        GROUPF(K, m + 7) LOADG(K, m + 15)
    }
    GROUPF(A, 56) GROUPF(B, 57) GROUPF(C, 58) GROUPF(E, 59)
    GROUPF(F, 60) GROUPF(G, 61) GROUPF(H, 62)
    // group 63: s = 505..510 (6 steps), window W=192 -> i=255 at lane 63
    SHIFTG(63)
    STEP_PQ(K0) STEP_QP(K1) STEP_PQ(K2) STEP_QP(K3) STEP_PQ(K4) STEP_QP(K5)

    if (l == 63) out[b] = p;               // dp[510][255]
#undef LOADG
#undef SHIFTG
#undef STEP_PQ
#undef STEP_QP
#undef GROUPF
}

// ---------------- Fallback (tiny ws): fused, D on the fly ----------------
__device__ __forceinline__ float cell_d(const float4* __restrict__ Xb,
                                        const float4* __restrict__ Yb,
                                        int i, int j)
{
    const float4* xr = Xb + i*16;
    const float4* yr = Yb + j*16;
    float acc = 0.f;
    #pragma unroll
    for (int k = 0; k < 16; ++k){
        float4 a = xr[k], bb = yr[k];
        float dx = a.x-bb.x, dy = a.y-bb.y, dz = a.z-bb.z, dw = a.w-bb.w;
        acc += dx*dx + dy*dy + dz*dz + dw*dw;
    }
    return acc;
}

__global__ __launch_bounds__(64) void ldtw_fused_fb(const float* __restrict__ X,
                                                    const float* __restrict__ Y,
                                                    float* __restrict__ out)
{
    const int b = blockIdx.x;
    const int l = threadIdx.x;
    const float4* Xb = (const float4*)(X + (size_t)b * NPT * 64);
    const float4* Yb = (const float4*)(Y + (size_t)b * NPT * 64);
    float prev1 = (l == 0) ? cell_d(Xb, Yb, 0, 0) : BIGV;
    float prev2 = BIGV;
    int base1 = 0, base2 = 0;
    for (int s = 1; s <= 510; ++s){
        const int im = imin_of(s);
        const int ix = imax_of(s);
        const int i  = im + l;
        const bool act = (i <= ix);
        const int ic = act ? i : ix;
        const int j  = s - ic;
        float Dv = cell_d(Xb, Yb, ic, j);
        const int d1 = im - base1, d2 = im - base2;
        float sr1 = dpp_shr1(prev1), sl1 = dpp_shl1(prev1);
        float sr2 = dpp_shr1(prev2), sl2 = dpp_shl1(prev2);
        float m1 = d1 ? fminf(prev1, sl1) : fminf(sr1, prev1);
        float vd = (d2 == 0) ? sr2 : ((d2 == 2) ? sl2 : prev2);
        float m3 = fminf(m1, vd);
        float cur = act ? (m3 + Dv) : BIGV;
        prev2 = prev1; base2 = base1;
        prev1 = cur;   base1 = im;
    }
    if (l == 0) out[b] = prev1;
}

extern "C" void kernel_launch(void* const* d_in, const int* in_sizes, int n_in,
                              void* d_out, int out_size, void* d_ws, size_t ws_size,
                              hipStream_t stream)
{
    const float* X = (const float*)d_in[0];
    const float* Y = (const float*)d_in[1];
    float* out = (float*)d_out;
    const int Bn = in_sizes[0] / (NPT * 64);     // = 16
    // Dwin: Bn * 512 rows * 64 f32 = 2 MiB; + slack for group-63 row-512 over-read
    const size_t need = (size_t)Bn * 512 * 64 * 4 + 65536;
    if (ws_size >= need && Bn == 16){
        float* Dwin = (float*)d_ws;
        hipLaunchKernelGGL(ldtw_dist, dim3(256), dim3(256), 0, stream, X, Y, Dwin);
        hipLaunchKernelGGL(ldtw_dp,   dim3(Bn),  dim3(64),  0, stream, Dwin, out);
    } else {
        hipLaunchKernelGGL(ldtw_fused_fb, dim3(Bn), dim3(64), 0, stream, X, Y, out);
    }
}